// Round 12
// baseline (137.972 us; speedup 1.0000x reference)
//
#include <hip/hip_runtime.h>

// LatentPositionModel ELBO:
//   out = sum_e [ d2_e + log1p(exp(-d2_e)) ]            (= -log_likelihood)
//       + 0.5 * sum_{n,d} [ exp(2*ls) + mu^2 - ls - 1 ] (= KL)
// N=100000, D=128, E=3200000.
//
// R12: int8 gather rows + v_dot4_i32_i8. d2 = s^2*(SSi + SSj - 2*dot(qi,qj)),
// SS = per-row sum of squares (int32 table, computed in the KL pass via
// 32-lane segmented shuffle reduce). Cuts ll's per-slot VALU ~5x vs fp8
// decode (R11 was ~64% VALUBusy). Scatter/overflow/validity unchanged.

#define NN 100000
#define DD 128
#define NBI 8
#define NBJ 16
#define NBINS 128
#define BSI 12500
#define BSJ 6250

// ---- tier A params ----
#define NKL 512                // kl blocks in front kernel
#define NSCA 1024              // scatter blocks
#define SLICEA 32u             // slots per (block,bin) = one 128B line
#define CAPA 32768u            // NSCA*SLICEA
#define OCAP 131072u           // global overflow list capacity (edges)
#define LOVF 768               // LDS overflow list capacity (edges)
#define SENT 0xFFFFFFFFu

#define QSCALE 21.166666f      // 127/6
#define S2Q    0.0022320293f   // (6/127)^2

// ---- tier B (R7) params ----
#define CAPB 26624u
#define NKLB 512
#define NSCB 1536

typedef unsigned int uint_t;
typedef float floatx2 __attribute__((ext_vector_type(2)));

// ---- ws layout tier A (bytes) ----
#define WA_OCURS  64
#define WA_SS     1024                       // int32[NN] = 400,000
#define WA_OFLOW  (WA_SS + 400384)           // uint2[OCAP] = 1,048,576
#define WA_MU8    (WA_OFLOW + 1048576)       // 12,800,000 (int8 rows)
#define WA_PAIRS  (WA_MU8 + 12800000)        // 128*32768*4 = 16,777,216
#define WA_END    (WA_PAIRS + 16777216)      // ~31.0 MB

// ---- ws layout tier B (R7, unchanged) ----
#define WB_CURSOR 256                        // uint[128] padded x16
#define WB_MU8    16384
#define WB_PAIRS  (WB_MU8 + 12800000)
#define PAIRB_BYTES (NBINS * (int)CAPB * 4)
#define WB_END    (WB_PAIRS + PAIRB_BYTES)

__device__ inline double block_reduce_add(double v) {
    for (int off = 32; off > 0; off >>= 1)
        v += __shfl_down(v, off, 64);
    __shared__ double lds[8];
    int wid  = threadIdx.x >> 6;
    int lane = threadIdx.x & 63;
    if (lane == 0) lds[wid] = v;
    __syncthreads();
    double r = 0.0;
    if (threadIdx.x == 0) {
        int nw = (blockDim.x + 63) >> 6;
        for (int w = 0; w < nw; ++w) r += lds[w];
    }
    return r;
}

__device__ inline double edge_term(float d2) {
    double t = (double)d2;
    if (d2 < 30.0f) t += (double)log1pf(expf(-d2));
    return t;
}

__device__ inline float d2_fp32(const float* __restrict__ mu, int i, int j) {
    const float* pa = mu + (size_t)i * DD;
    const float* pb = mu + (size_t)j * DD;
    float d2 = 0.0f;
    for (int d = 0; d < DD; ++d) {
        float df = pa[d] - pb[d];
        d2 += df * df;
    }
    return d2;
}

__device__ inline int dot4acc(unsigned int a, unsigned int b, int acc) {
#if __has_builtin(__builtin_amdgcn_sdot4)
    return __builtin_amdgcn_sdot4((int)a, (int)b, acc, false);
#else
    int s = acc;
    #pragma unroll
    for (int t = 0; t < 4; ++t) {
        int xa = (int)((a >> (8 * t)) & 0xFFu); xa = (xa ^ 0x80) - 0x80;
        int xb = (int)((b >> (8 * t)) & 0xFFu); xb = (xb ^ 0x80) - 0x80;
        s += xa * xb;
    }
    return s;
#endif
}

// fp8 decode path (tier B/C fallbacks only)
__device__ inline float d2_part(uint4 a, uint4 b) {
    float p = 0.0f;
    const unsigned int* pa = &a.x;
    const unsigned int* pb = &b.x;
    #pragma unroll
    for (int k = 0; k < 4; ++k) {
        floatx2 a0 = __builtin_amdgcn_cvt_pk_f32_fp8(pa[k], false);
        floatx2 a1 = __builtin_amdgcn_cvt_pk_f32_fp8(pa[k], true);
        floatx2 b0 = __builtin_amdgcn_cvt_pk_f32_fp8(pb[k], false);
        floatx2 b1 = __builtin_amdgcn_cvt_pk_f32_fp8(pb[k], true);
        float d0 = a0.x - b0.x;
        float d1 = a0.y - b0.y;
        float d2 = a1.x - b1.x;
        float d3 = a1.y - b1.y;
        p += d0 * d0 + d1 * d1 + d2 * d2 + d3 * d3;
    }
    return p;
}

// ---- Tier A fused front: blocks [0,NKL) = KL + int8 quant + SS;
//      blocks [NKL, NKL+NSCA) = LDS-staged scatter (stage init'd to SENT).
__global__ void front_kernel(const float* __restrict__ mu,
                             const float* __restrict__ ls,
                             unsigned int* __restrict__ mu8,
                             int* __restrict__ ssq,
                             const int* __restrict__ ei,
                             uint_t* __restrict__ pairs,
                             uint2* __restrict__ oflow,
                             uint_t* __restrict__ ocurs,
                             double* __restrict__ ws,
                             int total4, int E, int chunk) {
    __shared__ uint_t lcnt[NBINS];
    __shared__ uint_t stage[NBINS * (int)SLICEA];   // 16 KB
    __shared__ uint2  lovf[LOVF];                   // 6 KB
    __shared__ uint_t lovfc;
    __shared__ uint_t obase;
    double acc = 0.0;
    if (blockIdx.x < NKL) {
        // ---- KL + int8 quantize + per-row sum-of-squares ----
        int stride = NKL * blockDim.x;
        for (int i = blockIdx.x * blockDim.x + threadIdx.x; i < total4; i += stride) {
            float4 m = reinterpret_cast<const float4*>(mu)[i];
            float4 s = reinterpret_cast<const float4*>(ls)[i];
            float v;
            v  = 0.5f * (expf(2.0f * s.x) + m.x * m.x - s.x - 1.0f);
            v += 0.5f * (expf(2.0f * s.y) + m.y * m.y - s.y - 1.0f);
            v += 0.5f * (expf(2.0f * s.z) + m.z * m.z - s.z - 1.0f);
            v += 0.5f * (expf(2.0f * s.w) + m.w * m.w - s.w - 1.0f);
            acc += (double)v;
            int q0 = __float2int_rn(fminf(fmaxf(m.x * QSCALE, -127.f), 127.f));
            int q1 = __float2int_rn(fminf(fmaxf(m.y * QSCALE, -127.f), 127.f));
            int q2 = __float2int_rn(fminf(fmaxf(m.z * QSCALE, -127.f), 127.f));
            int q3 = __float2int_rn(fminf(fmaxf(m.w * QSCALE, -127.f), 127.f));
            unsigned int pk = (unsigned int)(q0 & 255) |
                              ((unsigned int)(q1 & 255) << 8) |
                              ((unsigned int)(q2 & 255) << 16) |
                              ((unsigned int)(q3 & 255) << 24);
            mu8[i] = pk;
            int pss = q0 * q0 + q1 * q1 + q2 * q2 + q3 * q3;
            #pragma unroll
            for (int mask = 16; mask >= 1; mask >>= 1)
                pss += __shfl_xor(pss, mask, 64);
            if ((threadIdx.x & 31) == 0) ssq[i >> 5] = pss;
        }
    } else {
        // ---- scatter: no global ops inside the loop ----
        int b = blockIdx.x - NKL;
        int t = threadIdx.x;
        for (int k = t; k < NBINS; k += blockDim.x) lcnt[k] = 0u;
        for (int k = t; k < NBINS * (int)SLICEA; k += blockDim.x) stage[k] = SENT;
        if (t == 0) lovfc = 0u;
        __syncthreads();
        int s = b * chunk, tend = min(E, s + chunk);
        for (int e = s + t; e < tend; e += blockDim.x) {
            int i = min(max(ei[e], 0), NN - 1);
            int j = min(max(ei[E + e], 0), NN - 1);
            int bi = i / BSI, bj = j / BSJ;
            int bin = bi * NBJ + bj;
            uint_t r = atomicAdd(&lcnt[bin], 1u);
            if (r < SLICEA) {
                stage[bin * (int)SLICEA + (int)r] =
                    ((uint_t)(i - bi * BSI) << 17) | (uint_t)j;   // < 2^31
            } else {
                uint_t ro = atomicAdd(&lovfc, 1u);
                if (ro < LOVF) {
                    lovf[ro] = make_uint2((uint_t)i, (uint_t)j);
                } else {
                    // adversarial-only: direct fp32 compute
                    acc += edge_term(d2_fp32(mu, i, j));
                }
            }
        }
        __syncthreads();
        // flush stage (SENT rides along in unfilled slots): full 128B lines
        for (int idx = t; idx < NBINS * (int)SLICEA; idx += blockDim.x) {
            int bin = idx >> 5, r = idx & 31;
            pairs[(size_t)bin * CAPA + (uint_t)b * SLICEA + (uint_t)r] = stage[idx];
        }
        // overflow: ONE global reservation per block, coalesced copy-out
        uint_t nov = min(lovfc, (uint_t)LOVF);
        if (t == 0 && nov) obase = atomicAdd(ocurs, nov);
        __syncthreads();
        if (nov) {
            uint_t bo = obase;
            for (uint_t o = t; o < nov; o += blockDim.x) {
                if (bo + o < OCAP) {
                    oflow[bo + o] = lovf[o];
                } else {
                    uint2 pr = lovf[o];
                    acc += edge_term(d2_fp32(mu, (int)pr.x, (int)pr.y));
                }
            }
        }
    }
    double r = block_reduce_add(acc);
    if (threadIdx.x == 0) atomicAdd(ws, r);
}

// Tier A ll: XCD k = blockIdx%8 owns slots [k*16*CAPA, (k+1)*16*CAPA).
// int8 rows; d2 = S2Q*(SSi + SSj - 2*dot). All loads unconditional;
// validity (sign bit) guards only the accumulation.
__global__ void ll_sortedA_kernel(const unsigned int* __restrict__ mu8,
                                  const int* __restrict__ ssq,
                                  const uint_t* __restrict__ pairs,
                                  const uint2* __restrict__ oflow,
                                  const uint_t* __restrict__ ocurs,
                                  double* __restrict__ ws) {
    int xcd  = blockIdx.x & 7;
    int lane = threadIdx.x & 7;
    unsigned int g  = (blockIdx.x >> 3) * (blockDim.x >> 3) + (threadIdx.x >> 3);
    unsigned int GP = (gridDim.x >> 3) * (blockDim.x >> 3);
    unsigned int gl = blockIdx.x * (blockDim.x >> 3) + (threadIdx.x >> 3);
    unsigned int GT = gridDim.x * (blockDim.x >> 3);
    unsigned int s    = (unsigned int)xcd * (NBJ * CAPA);
    unsigned int tend = s + NBJ * CAPA;
    unsigned int ibase = (unsigned int)(xcd * BSI);
    const uint4* tb = reinterpret_cast<const uint4*>(mu8);
    double acc = 0.0;
    for (unsigned int e0 = s + g; e0 < tend; e0 += 2u * GP) {
        unsigned int e1 = e0 + GP;
        uint_t p0 = pairs[e0];
        uint_t p1 = (e1 < tend) ? pairs[e1] : SENT;
        bool v0 = (p0 & 0x80000000u) == 0u;
        bool v1 = (p1 & 0x80000000u) == 0u;
        unsigned int i0 = min(ibase + (p0 >> 17), (unsigned int)(NN - 1));
        unsigned int j0 = min(p0 & 131071u,       (unsigned int)(NN - 1));
        unsigned int i1 = min(ibase + (p1 >> 17), (unsigned int)(NN - 1));
        unsigned int j1 = min(p1 & 131071u,       (unsigned int)(NN - 1));
        uint4 a0 = tb[(size_t)i0 * 8 + lane];
        uint4 b0 = tb[(size_t)j0 * 8 + lane];
        uint4 a1 = tb[(size_t)i1 * 8 + lane];
        uint4 b1 = tb[(size_t)j1 * 8 + lane];
        int sa0 = ssq[i0], sb0 = ssq[j0];
        int sa1 = ssq[i1], sb1 = ssq[j1];
        int d0 = 0, d1 = 0;
        d0 = dot4acc(a0.x, b0.x, d0);
        d0 = dot4acc(a0.y, b0.y, d0);
        d0 = dot4acc(a0.z, b0.z, d0);
        d0 = dot4acc(a0.w, b0.w, d0);
        d1 = dot4acc(a1.x, b1.x, d1);
        d1 = dot4acc(a1.y, b1.y, d1);
        d1 = dot4acc(a1.z, b1.z, d1);
        d1 = dot4acc(a1.w, b1.w, d1);
        #pragma unroll
        for (int m = 4; m >= 1; m >>= 1) {
            d0 += __shfl_xor(d0, m, 64);
            d1 += __shfl_xor(d1, m, 64);
        }
        if (lane == 0) {
            if (v0) acc += edge_term(S2Q * (float)(sa0 + sb0 - 2 * d0));
            if (v1) acc += edge_term(S2Q * (float)(sa1 + sb1 - 2 * d1));
        }
    }
    // overflow tail (few thousand edges; all groups machine-wide)
    unsigned int oc = min(*ocurs, OCAP);
    for (unsigned int o = gl; o < oc; o += GT) {
        uint2 pr = oflow[o];
        unsigned int i = min(pr.x, (unsigned int)(NN - 1));
        unsigned int j = min(pr.y, (unsigned int)(NN - 1));
        uint4 a = tb[(size_t)i * 8 + lane];
        uint4 b = tb[(size_t)j * 8 + lane];
        int sa = ssq[i], sb = ssq[j];
        int d = 0;
        d = dot4acc(a.x, b.x, d);
        d = dot4acc(a.y, b.y, d);
        d = dot4acc(a.z, b.z, d);
        d = dot4acc(a.w, b.w, d);
        #pragma unroll
        for (int m = 4; m >= 1; m >>= 1)
            d += __shfl_xor(d, m, 64);
        if (lane == 0) acc += edge_term(S2Q * (float)(sa + sb - 2 * d));
    }
    double r = block_reduce_add(acc);
    if (threadIdx.x == 0) atomicAdd(ws, r);
}

// ---- Tier B: exact R7 kernels (fp8) ----
__global__ void frontB_kernel(const float* __restrict__ mu,
                              const float* __restrict__ ls,
                              unsigned int* __restrict__ mu8,
                              const int* __restrict__ ei,
                              uint_t* __restrict__ pairs,
                              uint_t* __restrict__ cursor,
                              double* __restrict__ ws,
                              int total4, int E, int chunk) {
    __shared__ uint_t lh[NBINS];
    __shared__ uint_t lb[NBINS];
    double acc = 0.0;
    if (blockIdx.x < NKLB) {
        int stride = NKLB * blockDim.x;
        for (int i = blockIdx.x * blockDim.x + threadIdx.x; i < total4; i += stride) {
            float4 m = reinterpret_cast<const float4*>(mu)[i];
            float4 s = reinterpret_cast<const float4*>(ls)[i];
            float v;
            v  = 0.5f * (expf(2.0f * s.x) + m.x * m.x - s.x - 1.0f);
            v += 0.5f * (expf(2.0f * s.y) + m.y * m.y - s.y - 1.0f);
            v += 0.5f * (expf(2.0f * s.z) + m.z * m.z - s.z - 1.0f);
            v += 0.5f * (expf(2.0f * s.w) + m.w * m.w - s.w - 1.0f);
            acc += (double)v;
            int w = __builtin_amdgcn_cvt_pk_fp8_f32(m.x, m.y, 0, false);
            w     = __builtin_amdgcn_cvt_pk_fp8_f32(m.z, m.w, w, true);
            mu8[i] = (unsigned int)w;
        }
    } else {
        int b = blockIdx.x - NKLB;
        int t = threadIdx.x;
        for (int k = t; k < NBINS; k += blockDim.x) lh[k] = 0u;
        __syncthreads();
        int s = b * chunk, tend = min(E, s + chunk);
        for (int e = s + t; e < tend; e += blockDim.x) {
            int i = min(max(ei[e], 0), NN - 1);
            int j = min(max(ei[E + e], 0), NN - 1);
            atomicAdd(&lh[(i / BSI) * NBJ + j / BSJ], 1u);
        }
        __syncthreads();
        if (t < NBINS) lb[t] = atomicAdd(&cursor[t << 4], lh[t]);
        __syncthreads();
        if (t < NBINS) lh[t] = lb[t];
        __syncthreads();
        for (int e = s + t; e < tend; e += blockDim.x) {
            int i = min(max(ei[e], 0), NN - 1);
            int j = min(max(ei[E + e], 0), NN - 1);
            int bi = i / BSI, bj = j / BSJ;
            int bin = bi * NBJ + bj;
            uint_t r = atomicAdd(&lh[bin], 1u);
            if (r < CAPB) {
                pairs[(size_t)bin * CAPB + r] =
                    ((uint_t)(i - bi * BSI) << 17) | (uint_t)j;
            } else {
                acc += edge_term(d2_fp32(mu, i, j));
            }
        }
    }
    double r = block_reduce_add(acc);
    if (threadIdx.x == 0) atomicAdd(ws, r);
}

__global__ void ll_sortedB_kernel(const unsigned int* __restrict__ mu8,
                                  const uint_t* __restrict__ pairs,
                                  const uint_t* __restrict__ cursor,
                                  double* __restrict__ ws) {
    int xcd  = blockIdx.x & 7;
    int lane = threadIdx.x & 7;
    unsigned int g  = (blockIdx.x >> 3) * (blockDim.x >> 3) + (threadIdx.x >> 3);
    unsigned int GP = (gridDim.x >> 3) * (blockDim.x >> 3);
    unsigned int s    = (unsigned int)xcd * (NBJ * CAPB);
    unsigned int tend = s + NBJ * CAPB;
    unsigned int ibase = (unsigned int)(xcd * BSI);
    const uint4* tb = reinterpret_cast<const uint4*>(mu8);
    double acc = 0.0;
    for (unsigned int e0 = s + g; e0 < tend; e0 += 2u * GP) {
        unsigned int e1 = e0 + GP;
        unsigned int bin0 = e0 / CAPB, r0 = e0 - bin0 * CAPB;
        unsigned int bin1 = e1 / CAPB, r1 = e1 - bin1 * CAPB;
        unsigned int c0 = min(cursor[bin0 << 4], CAPB);
        bool v0 = r0 < c0;
        bool v1 = (e1 < tend) && (r1 < min(cursor[bin1 << 4], CAPB));
        if (v0) {
            uint_t p0 = pairs[e0];
            unsigned int i0 = min(ibase + (p0 >> 17), (unsigned int)(NN - 1));
            unsigned int j0 = min(p0 & 131071u,       (unsigned int)(NN - 1));
            uint4 a0 = tb[(size_t)i0 * 8 + lane];
            uint4 b0 = tb[(size_t)j0 * 8 + lane];
            float q0 = d2_part(a0, b0);
            #pragma unroll
            for (int m = 4; m >= 1; m >>= 1)
                q0 += __shfl_xor(q0, m, 64);
            if (lane == 0) acc += edge_term(q0);
        }
        if (v1) {
            uint_t p1 = pairs[e1];
            unsigned int i1 = min(ibase + (p1 >> 17), (unsigned int)(NN - 1));
            unsigned int j1 = min(p1 & 131071u,       (unsigned int)(NN - 1));
            uint4 a1 = tb[(size_t)i1 * 8 + lane];
            uint4 b1 = tb[(size_t)j1 * 8 + lane];
            float q1 = d2_part(a1, b1);
            #pragma unroll
            for (int m = 4; m >= 1; m >>= 1)
                q1 += __shfl_xor(q1, m, 64);
            if (lane == 0) acc += edge_term(q1);
        }
    }
    double r = block_reduce_add(acc);
    if (threadIdx.x == 0) atomicAdd(ws, r);
}

// ---- fallback paths ----
__global__ void kl_conv_kernel(const float* __restrict__ mu,
                               const float* __restrict__ ls,
                               unsigned int* __restrict__ mu8,
                               double* __restrict__ ws, int total4) {
    int stride = gridDim.x * blockDim.x;
    double acc = 0.0;
    for (int i = blockIdx.x * blockDim.x + threadIdx.x; i < total4; i += stride) {
        float4 m = reinterpret_cast<const float4*>(mu)[i];
        float4 s = reinterpret_cast<const float4*>(ls)[i];
        float v;
        v  = 0.5f * (expf(2.0f * s.x) + m.x * m.x - s.x - 1.0f);
        v += 0.5f * (expf(2.0f * s.y) + m.y * m.y - s.y - 1.0f);
        v += 0.5f * (expf(2.0f * s.z) + m.z * m.z - s.z - 1.0f);
        v += 0.5f * (expf(2.0f * s.w) + m.w * m.w - s.w - 1.0f);
        acc += (double)v;
        if (mu8) {
            int w = __builtin_amdgcn_cvt_pk_fp8_f32(m.x, m.y, 0, false);
            w     = __builtin_amdgcn_cvt_pk_fp8_f32(m.z, m.w, w, true);
            mu8[i] = (unsigned int)w;
        }
    }
    double r = block_reduce_add(acc);
    if (threadIdx.x == 0) atomicAdd(ws, r);
}

__global__ void ll8_kernel(const unsigned int* __restrict__ mu8,
                           const int* __restrict__ ei,
                           double* __restrict__ ws, int E) {
    int gid     = (blockIdx.x * blockDim.x + threadIdx.x) >> 3;
    int lane    = threadIdx.x & 7;
    int ngroups = (gridDim.x * blockDim.x) >> 3;
    double acc = 0.0;
    const uint4* base = reinterpret_cast<const uint4*>(mu8);
    for (int e = gid; e < E; e += 2 * ngroups) {
        int e1 = e + ngroups;
        bool has2 = e1 < E;
        int i0 = min(max(ei[e], 0), NN - 1);
        int j0 = min(max(ei[E + e], 0), NN - 1);
        int i1 = has2 ? min(max(ei[e1], 0), NN - 1) : i0;
        int j1 = has2 ? min(max(ei[E + e1], 0), NN - 1) : j0;
        uint4 a0 = base[(size_t)i0 * 8 + lane];
        uint4 b0 = base[(size_t)j0 * 8 + lane];
        uint4 a1 = base[(size_t)i1 * 8 + lane];
        uint4 b1 = base[(size_t)j1 * 8 + lane];
        float p0 = d2_part(a0, b0);
        float p1 = d2_part(a1, b1);
        #pragma unroll
        for (int m = 4; m >= 1; m >>= 1) {
            p0 += __shfl_xor(p0, m, 64);
            p1 += __shfl_xor(p1, m, 64);
        }
        if (lane == 0) {
            acc += edge_term(p0);
            if (has2) acc += edge_term(p1);
        }
    }
    double r = block_reduce_add(acc);
    if (threadIdx.x == 0) atomicAdd(ws, r);
}

__global__ void ll32_kernel(const float* __restrict__ mu,
                            const int* __restrict__ ei,
                            double* __restrict__ ws, int E) {
    int gid     = (blockIdx.x * blockDim.x + threadIdx.x) >> 5;
    int lane    = threadIdx.x & 31;
    int ngroups = (gridDim.x * blockDim.x) >> 5;
    double acc = 0.0;
    for (int e = gid; e < E; e += ngroups) {
        int i = min(max(ei[e], 0), NN - 1);
        int j = min(max(ei[E + e], 0), NN - 1);
        const float4* a = reinterpret_cast<const float4*>(mu + (size_t)i * DD);
        const float4* b = reinterpret_cast<const float4*>(mu + (size_t)j * DD);
        float4 av = a[lane];
        float4 bv = b[lane];
        float dx = av.x - bv.x;
        float dy = av.y - bv.y;
        float dz = av.z - bv.z;
        float dw = av.w - bv.w;
        float p = dx * dx + dy * dy + dz * dz + dw * dw;
        for (int m = 16; m >= 1; m >>= 1)
            p += __shfl_xor(p, m, 64);
        if (lane == 0)
            acc += edge_term(p);
    }
    double r = block_reduce_add(acc);
    if (threadIdx.x == 0) atomicAdd(ws, r);
}

__global__ void init_kernel(double* ws, float* out) {
    if (threadIdx.x == 0) { ws[0] = 0.0; out[0] = 0.0f; }
}

__global__ void finalize_kernel(const double* __restrict__ ws,
                                float* __restrict__ out) {
    if (blockIdx.x == 0 && threadIdx.x == 0)
        out[0] = (float)ws[0];
}

extern "C" void kernel_launch(void* const* d_in, const int* in_sizes, int n_in,
                              void* d_out, int out_size, void* d_ws, size_t ws_size,
                              hipStream_t stream) {
    const float* mu = (const float*)d_in[0];
    const float* ls = (const float*)d_in[1];
    const int*   ei = (const int*)d_in[2];
    float* out = (float*)d_out;
    char*  wsb = (char*)d_ws;
    double* ws = (double*)d_ws;

    const int E = in_sizes[2] / 2;          // edge_index is [2, E]
    const int total4 = (NN * DD) / 4;

    if (ws_size >= (size_t)WA_END) {
        // ---- Tier A (int8 + dot4) ----
        uint_t* ocurs = reinterpret_cast<uint_t*>(wsb + WA_OCURS);
        int*    ssq   = reinterpret_cast<int*>(wsb + WA_SS);
        uint2*  oflow = reinterpret_cast<uint2*>(wsb + WA_OFLOW);
        unsigned int* mu8 = reinterpret_cast<unsigned int*>(wsb + WA_MU8);
        uint_t* pairs = reinterpret_cast<uint_t*>(wsb + WA_PAIRS);
        const int chunk = (E + NSCA - 1) / NSCA;

        hipMemsetAsync(wsb, 0, 1024, stream);          // acc + ocurs
        front_kernel<<<NKL + NSCA, 256, 0, stream>>>(mu, ls, mu8, ssq, ei, pairs,
                                                     oflow, ocurs, ws,
                                                     total4, E, chunk);
        ll_sortedA_kernel<<<2048, 256, 0, stream>>>(mu8, ssq, pairs,
                                                    oflow, ocurs, ws);
    } else if (ws_size >= (size_t)WB_END) {
        // ---- Tier B (R7, fp8) ----
        uint_t* cursor = reinterpret_cast<uint_t*>(wsb + WB_CURSOR);
        unsigned int* mu8 = reinterpret_cast<unsigned int*>(wsb + WB_MU8);
        uint_t* pairs = reinterpret_cast<uint_t*>(wsb + WB_PAIRS);
        const int chunk = (E + NSCB - 1) / NSCB;

        hipMemsetAsync(wsb, 0, 16384, stream);
        frontB_kernel<<<NKLB + NSCB, 256, 0, stream>>>(mu, ls, mu8, ei, pairs,
                                                       cursor, ws, total4, E, chunk);
        ll_sortedB_kernel<<<2048, 256, 0, stream>>>(mu8, pairs, cursor, ws);
    } else {
        const bool use_fp8 = (ws_size >= (size_t)WB_MU8 + 12800000u);
        unsigned int* mu8 = use_fp8
            ? reinterpret_cast<unsigned int*>(wsb + WB_MU8) : nullptr;
        init_kernel<<<1, 64, 0, stream>>>(ws, out);
        kl_conv_kernel<<<1024, 256, 0, stream>>>(mu, ls, mu8, ws, total4);
        if (use_fp8)
            ll8_kernel<<<2048, 256, 0, stream>>>(mu8, ei, ws, E);
        else
            ll32_kernel<<<2048, 256, 0, stream>>>(mu, ei, ws, E);
    }
    finalize_kernel<<<1, 64, 0, stream>>>(ws, out);
}

// Round 13
// 106.233 us; speedup vs baseline: 1.2988x; 1.2988x over previous
//
#include <hip/hip_runtime.h>

// LatentPositionModel ELBO:
//   out = sum_e [ d2_e + log1p(exp(-d2_e)) ]            (= -log_likelihood)
//       + 0.5 * sum_{n,d} [ exp(2*ls) + mu^2 - ls - 1 ] (= KL)
// N=100000, D=128, E=3200000.
//
// R13: (a) ssq table deleted — d2 = S2Q*(dot(a,a)+dot(b,b)-2dot(a,b)) computed
// entirely from gathered int8 rows (removes 2 scattered dependent loads/slot;
// VALU had 70% headroom in R12). (b) 4-slot unroll: 4 pairs + 8 row gathers
// in flight per iteration (2x independent work per latency chain).

#define NN 100000
#define DD 128
#define NBI 8
#define NBJ 16
#define NBINS 128
#define BSI 12500
#define BSJ 6250

// ---- tier A params ----
#define NKL 512                // kl blocks in front kernel
#define NSCA 1024              // scatter blocks
#define SLICEA 32u             // slots per (block,bin) = one 128B line
#define CAPA 32768u            // NSCA*SLICEA
#define OCAP 131072u           // global overflow list capacity (edges)
#define LOVF 768               // LDS overflow list capacity (edges)
#define SENT 0xFFFFFFFFu

#define QSCALE 21.166666f      // 127/6
#define S2Q    0.0022320293f   // (6/127)^2

// ---- tier B (R7) params ----
#define CAPB 26624u
#define NKLB 512
#define NSCB 1536

typedef unsigned int uint_t;
typedef float floatx2 __attribute__((ext_vector_type(2)));

// ---- ws layout tier A (bytes) ----
#define WA_OCURS  64
#define WA_OFLOW  1024                       // uint2[OCAP] = 1,048,576
#define WA_MU8    (WA_OFLOW + 1048576)       // 12,800,000 (int8 rows)
#define WA_PAIRS  (WA_MU8 + 12800000)        // 128*32768*4 = 16,777,216
#define WA_END    (WA_PAIRS + 16777216)      // 30,626,816 B

// ---- ws layout tier B (R7, unchanged) ----
#define WB_CURSOR 256                        // uint[128] padded x16
#define WB_MU8    16384
#define WB_PAIRS  (WB_MU8 + 12800000)
#define PAIRB_BYTES (NBINS * (int)CAPB * 4)
#define WB_END    (WB_PAIRS + PAIRB_BYTES)

__device__ inline double block_reduce_add(double v) {
    for (int off = 32; off > 0; off >>= 1)
        v += __shfl_down(v, off, 64);
    __shared__ double lds[8];
    int wid  = threadIdx.x >> 6;
    int lane = threadIdx.x & 63;
    if (lane == 0) lds[wid] = v;
    __syncthreads();
    double r = 0.0;
    if (threadIdx.x == 0) {
        int nw = (blockDim.x + 63) >> 6;
        for (int w = 0; w < nw; ++w) r += lds[w];
    }
    return r;
}

__device__ inline double edge_term(float d2) {
    double t = (double)d2;
    if (d2 < 30.0f) t += (double)log1pf(expf(-d2));
    return t;
}

__device__ inline float d2_fp32(const float* __restrict__ mu, int i, int j) {
    const float* pa = mu + (size_t)i * DD;
    const float* pb = mu + (size_t)j * DD;
    float d2 = 0.0f;
    for (int d = 0; d < DD; ++d) {
        float df = pa[d] - pb[d];
        d2 += df * df;
    }
    return d2;
}

__device__ inline int dot4acc(unsigned int a, unsigned int b, int acc) {
#if __has_builtin(__builtin_amdgcn_sdot4)
    return __builtin_amdgcn_sdot4((int)a, (int)b, acc, false);
#else
    int s = acc;
    #pragma unroll
    for (int t = 0; t < 4; ++t) {
        int xa = (int)((a >> (8 * t)) & 0xFFu); xa = (xa ^ 0x80) - 0x80;
        int xb = (int)((b >> (8 * t)) & 0xFFu); xb = (xb ^ 0x80) - 0x80;
        s += xa * xb;
    }
    return s;
#endif
}

// per-lane partial: dot(a,a) + dot(b,b) - 2*dot(a,b) over 16 bytes
__device__ inline int d2_int_part(uint4 a, uint4 b) {
    int daa = 0, dbb = 0, dab = 0;
    daa = dot4acc(a.x, a.x, daa); daa = dot4acc(a.y, a.y, daa);
    daa = dot4acc(a.z, a.z, daa); daa = dot4acc(a.w, a.w, daa);
    dbb = dot4acc(b.x, b.x, dbb); dbb = dot4acc(b.y, b.y, dbb);
    dbb = dot4acc(b.z, b.z, dbb); dbb = dot4acc(b.w, b.w, dbb);
    dab = dot4acc(a.x, b.x, dab); dab = dot4acc(a.y, b.y, dab);
    dab = dot4acc(a.z, b.z, dab); dab = dot4acc(a.w, b.w, dab);
    return daa + dbb - 2 * dab;
}

// fp8 decode path (tier B/C fallbacks only)
__device__ inline float d2_part(uint4 a, uint4 b) {
    float p = 0.0f;
    const unsigned int* pa = &a.x;
    const unsigned int* pb = &b.x;
    #pragma unroll
    for (int k = 0; k < 4; ++k) {
        floatx2 a0 = __builtin_amdgcn_cvt_pk_f32_fp8(pa[k], false);
        floatx2 a1 = __builtin_amdgcn_cvt_pk_f32_fp8(pa[k], true);
        floatx2 b0 = __builtin_amdgcn_cvt_pk_f32_fp8(pb[k], false);
        floatx2 b1 = __builtin_amdgcn_cvt_pk_f32_fp8(pb[k], true);
        float d0 = a0.x - b0.x;
        float d1 = a0.y - b0.y;
        float d2 = a1.x - b1.x;
        float d3 = a1.y - b1.y;
        p += d0 * d0 + d1 * d1 + d2 * d2 + d3 * d3;
    }
    return p;
}

// ---- Tier A fused front: blocks [0,NKL) = KL + int8 quant;
//      blocks [NKL, NKL+NSCA) = LDS-staged scatter (stage init'd to SENT).
__global__ void front_kernel(const float* __restrict__ mu,
                             const float* __restrict__ ls,
                             unsigned int* __restrict__ mu8,
                             const int* __restrict__ ei,
                             uint_t* __restrict__ pairs,
                             uint2* __restrict__ oflow,
                             uint_t* __restrict__ ocurs,
                             double* __restrict__ ws,
                             int total4, int E, int chunk) {
    __shared__ uint_t lcnt[NBINS];
    __shared__ uint_t stage[NBINS * (int)SLICEA];   // 16 KB
    __shared__ uint2  lovf[LOVF];                   // 6 KB
    __shared__ uint_t lovfc;
    __shared__ uint_t obase;
    double acc = 0.0;
    if (blockIdx.x < NKL) {
        // ---- KL + int8 quantize ----
        int stride = NKL * blockDim.x;
        for (int i = blockIdx.x * blockDim.x + threadIdx.x; i < total4; i += stride) {
            float4 m = reinterpret_cast<const float4*>(mu)[i];
            float4 s = reinterpret_cast<const float4*>(ls)[i];
            float v;
            v  = 0.5f * (expf(2.0f * s.x) + m.x * m.x - s.x - 1.0f);
            v += 0.5f * (expf(2.0f * s.y) + m.y * m.y - s.y - 1.0f);
            v += 0.5f * (expf(2.0f * s.z) + m.z * m.z - s.z - 1.0f);
            v += 0.5f * (expf(2.0f * s.w) + m.w * m.w - s.w - 1.0f);
            acc += (double)v;
            int q0 = __float2int_rn(fminf(fmaxf(m.x * QSCALE, -127.f), 127.f));
            int q1 = __float2int_rn(fminf(fmaxf(m.y * QSCALE, -127.f), 127.f));
            int q2 = __float2int_rn(fminf(fmaxf(m.z * QSCALE, -127.f), 127.f));
            int q3 = __float2int_rn(fminf(fmaxf(m.w * QSCALE, -127.f), 127.f));
            unsigned int pk = (unsigned int)(q0 & 255) |
                              ((unsigned int)(q1 & 255) << 8) |
                              ((unsigned int)(q2 & 255) << 16) |
                              ((unsigned int)(q3 & 255) << 24);
            mu8[i] = pk;
        }
    } else {
        // ---- scatter: no global ops inside the loop ----
        int b = blockIdx.x - NKL;
        int t = threadIdx.x;
        for (int k = t; k < NBINS; k += blockDim.x) lcnt[k] = 0u;
        for (int k = t; k < NBINS * (int)SLICEA; k += blockDim.x) stage[k] = SENT;
        if (t == 0) lovfc = 0u;
        __syncthreads();
        int s = b * chunk, tend = min(E, s + chunk);
        for (int e = s + t; e < tend; e += blockDim.x) {
            int i = min(max(ei[e], 0), NN - 1);
            int j = min(max(ei[E + e], 0), NN - 1);
            int bi = i / BSI, bj = j / BSJ;
            int bin = bi * NBJ + bj;
            uint_t r = atomicAdd(&lcnt[bin], 1u);
            if (r < SLICEA) {
                stage[bin * (int)SLICEA + (int)r] =
                    ((uint_t)(i - bi * BSI) << 17) | (uint_t)j;   // < 2^31
            } else {
                uint_t ro = atomicAdd(&lovfc, 1u);
                if (ro < LOVF) {
                    lovf[ro] = make_uint2((uint_t)i, (uint_t)j);
                } else {
                    // adversarial-only: direct fp32 compute
                    acc += edge_term(d2_fp32(mu, i, j));
                }
            }
        }
        __syncthreads();
        // flush stage (SENT rides along in unfilled slots): full 128B lines
        for (int idx = t; idx < NBINS * (int)SLICEA; idx += blockDim.x) {
            int bin = idx >> 5, r = idx & 31;
            pairs[(size_t)bin * CAPA + (uint_t)b * SLICEA + (uint_t)r] = stage[idx];
        }
        // overflow: ONE global reservation per block, coalesced copy-out
        uint_t nov = min(lovfc, (uint_t)LOVF);
        if (t == 0 && nov) obase = atomicAdd(ocurs, nov);
        __syncthreads();
        if (nov) {
            uint_t bo = obase;
            for (uint_t o = t; o < nov; o += blockDim.x) {
                if (bo + o < OCAP) {
                    oflow[bo + o] = lovf[o];
                } else {
                    uint2 pr = lovf[o];
                    acc += edge_term(d2_fp32(mu, (int)pr.x, (int)pr.y));
                }
            }
        }
    }
    double r = block_reduce_add(acc);
    if (threadIdx.x == 0) atomicAdd(ws, r);
}

// Tier A ll: XCD k = blockIdx%8 owns slots [k*16*CAPA, (k+1)*16*CAPA).
// 4-slot unroll: 4 pairs + 8 row gathers issued back-to-back; d2 computed
// entirely from rows (no ssq). Validity (sign bit) guards accumulation only.
__global__ void ll_sortedA_kernel(const unsigned int* __restrict__ mu8,
                                  const uint_t* __restrict__ pairs,
                                  const uint2* __restrict__ oflow,
                                  const uint_t* __restrict__ ocurs,
                                  double* __restrict__ ws) {
    int xcd  = blockIdx.x & 7;
    int lane = threadIdx.x & 7;
    unsigned int g  = (blockIdx.x >> 3) * (blockDim.x >> 3) + (threadIdx.x >> 3);
    unsigned int GP = (gridDim.x >> 3) * (blockDim.x >> 3);
    unsigned int gl = blockIdx.x * (blockDim.x >> 3) + (threadIdx.x >> 3);
    unsigned int GT = gridDim.x * (blockDim.x >> 3);
    unsigned int s    = (unsigned int)xcd * (NBJ * CAPA);
    unsigned int tend = s + NBJ * CAPA;
    unsigned int ibase = (unsigned int)(xcd * BSI);
    const uint4* tb = reinterpret_cast<const uint4*>(mu8);
    double acc = 0.0;
    for (unsigned int e0 = s + g; e0 < tend; e0 += 4u * GP) {
        unsigned int e1 = e0 + GP;
        unsigned int e2 = e0 + 2u * GP;
        unsigned int e3 = e0 + 3u * GP;
        uint_t p0 = pairs[e0];
        uint_t p1 = (e1 < tend) ? pairs[e1] : SENT;
        uint_t p2 = (e2 < tend) ? pairs[e2] : SENT;
        uint_t p3 = (e3 < tend) ? pairs[e3] : SENT;
        unsigned int i0 = min(ibase + (p0 >> 17), (unsigned int)(NN - 1));
        unsigned int j0 = min(p0 & 131071u,       (unsigned int)(NN - 1));
        unsigned int i1 = min(ibase + (p1 >> 17), (unsigned int)(NN - 1));
        unsigned int j1 = min(p1 & 131071u,       (unsigned int)(NN - 1));
        unsigned int i2 = min(ibase + (p2 >> 17), (unsigned int)(NN - 1));
        unsigned int j2 = min(p2 & 131071u,       (unsigned int)(NN - 1));
        unsigned int i3 = min(ibase + (p3 >> 17), (unsigned int)(NN - 1));
        unsigned int j3 = min(p3 & 131071u,       (unsigned int)(NN - 1));
        uint4 a0 = tb[(size_t)i0 * 8 + lane];
        uint4 b0 = tb[(size_t)j0 * 8 + lane];
        uint4 a1 = tb[(size_t)i1 * 8 + lane];
        uint4 b1 = tb[(size_t)j1 * 8 + lane];
        uint4 a2 = tb[(size_t)i2 * 8 + lane];
        uint4 b2 = tb[(size_t)j2 * 8 + lane];
        uint4 a3 = tb[(size_t)i3 * 8 + lane];
        uint4 b3 = tb[(size_t)j3 * 8 + lane];
        int d0 = d2_int_part(a0, b0);
        int d1 = d2_int_part(a1, b1);
        int d2 = d2_int_part(a2, b2);
        int d3 = d2_int_part(a3, b3);
        #pragma unroll
        for (int m = 4; m >= 1; m >>= 1) {
            d0 += __shfl_xor(d0, m, 64);
            d1 += __shfl_xor(d1, m, 64);
            d2 += __shfl_xor(d2, m, 64);
            d3 += __shfl_xor(d3, m, 64);
        }
        if (lane == 0) {
            if (!(p0 & 0x80000000u)) acc += edge_term(S2Q * (float)d0);
            if (!(p1 & 0x80000000u)) acc += edge_term(S2Q * (float)d1);
            if (!(p2 & 0x80000000u)) acc += edge_term(S2Q * (float)d2);
            if (!(p3 & 0x80000000u)) acc += edge_term(S2Q * (float)d3);
        }
    }
    // overflow tail (few thousand edges; all groups machine-wide)
    unsigned int oc = min(*ocurs, OCAP);
    for (unsigned int o = gl; o < oc; o += GT) {
        uint2 pr = oflow[o];
        unsigned int i = min(pr.x, (unsigned int)(NN - 1));
        unsigned int j = min(pr.y, (unsigned int)(NN - 1));
        uint4 a = tb[(size_t)i * 8 + lane];
        uint4 b = tb[(size_t)j * 8 + lane];
        int d = d2_int_part(a, b);
        #pragma unroll
        for (int m = 4; m >= 1; m >>= 1)
            d += __shfl_xor(d, m, 64);
        if (lane == 0) acc += edge_term(S2Q * (float)d);
    }
    double r = block_reduce_add(acc);
    if (threadIdx.x == 0) atomicAdd(ws, r);
}

// ---- Tier B: exact R7 kernels (fp8) ----
__global__ void frontB_kernel(const float* __restrict__ mu,
                              const float* __restrict__ ls,
                              unsigned int* __restrict__ mu8,
                              const int* __restrict__ ei,
                              uint_t* __restrict__ pairs,
                              uint_t* __restrict__ cursor,
                              double* __restrict__ ws,
                              int total4, int E, int chunk) {
    __shared__ uint_t lh[NBINS];
    __shared__ uint_t lb[NBINS];
    double acc = 0.0;
    if (blockIdx.x < NKLB) {
        int stride = NKLB * blockDim.x;
        for (int i = blockIdx.x * blockDim.x + threadIdx.x; i < total4; i += stride) {
            float4 m = reinterpret_cast<const float4*>(mu)[i];
            float4 s = reinterpret_cast<const float4*>(ls)[i];
            float v;
            v  = 0.5f * (expf(2.0f * s.x) + m.x * m.x - s.x - 1.0f);
            v += 0.5f * (expf(2.0f * s.y) + m.y * m.y - s.y - 1.0f);
            v += 0.5f * (expf(2.0f * s.z) + m.z * m.z - s.z - 1.0f);
            v += 0.5f * (expf(2.0f * s.w) + m.w * m.w - s.w - 1.0f);
            acc += (double)v;
            int w = __builtin_amdgcn_cvt_pk_fp8_f32(m.x, m.y, 0, false);
            w     = __builtin_amdgcn_cvt_pk_fp8_f32(m.z, m.w, w, true);
            mu8[i] = (unsigned int)w;
        }
    } else {
        int b = blockIdx.x - NKLB;
        int t = threadIdx.x;
        for (int k = t; k < NBINS; k += blockDim.x) lh[k] = 0u;
        __syncthreads();
        int s = b * chunk, tend = min(E, s + chunk);
        for (int e = s + t; e < tend; e += blockDim.x) {
            int i = min(max(ei[e], 0), NN - 1);
            int j = min(max(ei[E + e], 0), NN - 1);
            atomicAdd(&lh[(i / BSI) * NBJ + j / BSJ], 1u);
        }
        __syncthreads();
        if (t < NBINS) lb[t] = atomicAdd(&cursor[t << 4], lh[t]);
        __syncthreads();
        if (t < NBINS) lh[t] = lb[t];
        __syncthreads();
        for (int e = s + t; e < tend; e += blockDim.x) {
            int i = min(max(ei[e], 0), NN - 1);
            int j = min(max(ei[E + e], 0), NN - 1);
            int bi = i / BSI, bj = j / BSJ;
            int bin = bi * NBJ + bj;
            uint_t r = atomicAdd(&lh[bin], 1u);
            if (r < CAPB) {
                pairs[(size_t)bin * CAPB + r] =
                    ((uint_t)(i - bi * BSI) << 17) | (uint_t)j;
            } else {
                acc += edge_term(d2_fp32(mu, i, j));
            }
        }
    }
    double r = block_reduce_add(acc);
    if (threadIdx.x == 0) atomicAdd(ws, r);
}

__global__ void ll_sortedB_kernel(const unsigned int* __restrict__ mu8,
                                  const uint_t* __restrict__ pairs,
                                  const uint_t* __restrict__ cursor,
                                  double* __restrict__ ws) {
    int xcd  = blockIdx.x & 7;
    int lane = threadIdx.x & 7;
    unsigned int g  = (blockIdx.x >> 3) * (blockDim.x >> 3) + (threadIdx.x >> 3);
    unsigned int GP = (gridDim.x >> 3) * (blockDim.x >> 3);
    unsigned int s    = (unsigned int)xcd * (NBJ * CAPB);
    unsigned int tend = s + NBJ * CAPB;
    unsigned int ibase = (unsigned int)(xcd * BSI);
    const uint4* tb = reinterpret_cast<const uint4*>(mu8);
    double acc = 0.0;
    for (unsigned int e0 = s + g; e0 < tend; e0 += 2u * GP) {
        unsigned int e1 = e0 + GP;
        unsigned int bin0 = e0 / CAPB, r0 = e0 - bin0 * CAPB;
        unsigned int bin1 = e1 / CAPB, r1 = e1 - bin1 * CAPB;
        unsigned int c0 = min(cursor[bin0 << 4], CAPB);
        bool v0 = r0 < c0;
        bool v1 = (e1 < tend) && (r1 < min(cursor[bin1 << 4], CAPB));
        if (v0) {
            uint_t p0 = pairs[e0];
            unsigned int i0 = min(ibase + (p0 >> 17), (unsigned int)(NN - 1));
            unsigned int j0 = min(p0 & 131071u,       (unsigned int)(NN - 1));
            uint4 a0 = tb[(size_t)i0 * 8 + lane];
            uint4 b0 = tb[(size_t)j0 * 8 + lane];
            float q0 = d2_part(a0, b0);
            #pragma unroll
            for (int m = 4; m >= 1; m >>= 1)
                q0 += __shfl_xor(q0, m, 64);
            if (lane == 0) acc += edge_term(q0);
        }
        if (v1) {
            uint_t p1 = pairs[e1];
            unsigned int i1 = min(ibase + (p1 >> 17), (unsigned int)(NN - 1));
            unsigned int j1 = min(p1 & 131071u,       (unsigned int)(NN - 1));
            uint4 a1 = tb[(size_t)i1 * 8 + lane];
            uint4 b1 = tb[(size_t)j1 * 8 + lane];
            float q1 = d2_part(a1, b1);
            #pragma unroll
            for (int m = 4; m >= 1; m >>= 1)
                q1 += __shfl_xor(q1, m, 64);
            if (lane == 0) acc += edge_term(q1);
        }
    }
    double r = block_reduce_add(acc);
    if (threadIdx.x == 0) atomicAdd(ws, r);
}

// ---- fallback paths ----
__global__ void kl_conv_kernel(const float* __restrict__ mu,
                               const float* __restrict__ ls,
                               unsigned int* __restrict__ mu8,
                               double* __restrict__ ws, int total4) {
    int stride = gridDim.x * blockDim.x;
    double acc = 0.0;
    for (int i = blockIdx.x * blockDim.x + threadIdx.x; i < total4; i += stride) {
        float4 m = reinterpret_cast<const float4*>(mu)[i];
        float4 s = reinterpret_cast<const float4*>(ls)[i];
        float v;
        v  = 0.5f * (expf(2.0f * s.x) + m.x * m.x - s.x - 1.0f);
        v += 0.5f * (expf(2.0f * s.y) + m.y * m.y - s.y - 1.0f);
        v += 0.5f * (expf(2.0f * s.z) + m.z * m.z - s.z - 1.0f);
        v += 0.5f * (expf(2.0f * s.w) + m.w * m.w - s.w - 1.0f);
        acc += (double)v;
        if (mu8) {
            int w = __builtin_amdgcn_cvt_pk_fp8_f32(m.x, m.y, 0, false);
            w     = __builtin_amdgcn_cvt_pk_fp8_f32(m.z, m.w, w, true);
            mu8[i] = (unsigned int)w;
        }
    }
    double r = block_reduce_add(acc);
    if (threadIdx.x == 0) atomicAdd(ws, r);
}

__global__ void ll8_kernel(const unsigned int* __restrict__ mu8,
                           const int* __restrict__ ei,
                           double* __restrict__ ws, int E) {
    int gid     = (blockIdx.x * blockDim.x + threadIdx.x) >> 3;
    int lane    = threadIdx.x & 7;
    int ngroups = (gridDim.x * blockDim.x) >> 3;
    double acc = 0.0;
    const uint4* base = reinterpret_cast<const uint4*>(mu8);
    for (int e = gid; e < E; e += 2 * ngroups) {
        int e1 = e + ngroups;
        bool has2 = e1 < E;
        int i0 = min(max(ei[e], 0), NN - 1);
        int j0 = min(max(ei[E + e], 0), NN - 1);
        int i1 = has2 ? min(max(ei[e1], 0), NN - 1) : i0;
        int j1 = has2 ? min(max(ei[E + e1], 0), NN - 1) : j0;
        uint4 a0 = base[(size_t)i0 * 8 + lane];
        uint4 b0 = base[(size_t)j0 * 8 + lane];
        uint4 a1 = base[(size_t)i1 * 8 + lane];
        uint4 b1 = base[(size_t)j1 * 8 + lane];
        float p0 = d2_part(a0, b0);
        float p1 = d2_part(a1, b1);
        #pragma unroll
        for (int m = 4; m >= 1; m >>= 1) {
            p0 += __shfl_xor(p0, m, 64);
            p1 += __shfl_xor(p1, m, 64);
        }
        if (lane == 0) {
            acc += edge_term(p0);
            if (has2) acc += edge_term(p1);
        }
    }
    double r = block_reduce_add(acc);
    if (threadIdx.x == 0) atomicAdd(ws, r);
}

__global__ void ll32_kernel(const float* __restrict__ mu,
                            const int* __restrict__ ei,
                            double* __restrict__ ws, int E) {
    int gid     = (blockIdx.x * blockDim.x + threadIdx.x) >> 5;
    int lane    = threadIdx.x & 31;
    int ngroups = (gridDim.x * blockDim.x) >> 5;
    double acc = 0.0;
    for (int e = gid; e < E; e += ngroups) {
        int i = min(max(ei[e], 0), NN - 1);
        int j = min(max(ei[E + e], 0), NN - 1);
        const float4* a = reinterpret_cast<const float4*>(mu + (size_t)i * DD);
        const float4* b = reinterpret_cast<const float4*>(mu + (size_t)j * DD);
        float4 av = a[lane];
        float4 bv = b[lane];
        float dx = av.x - bv.x;
        float dy = av.y - bv.y;
        float dz = av.z - bv.z;
        float dw = av.w - bv.w;
        float p = dx * dx + dy * dy + dz * dz + dw * dw;
        for (int m = 16; m >= 1; m >>= 1)
            p += __shfl_xor(p, m, 64);
        if (lane == 0)
            acc += edge_term(p);
    }
    double r = block_reduce_add(acc);
    if (threadIdx.x == 0) atomicAdd(ws, r);
}

__global__ void init_kernel(double* ws, float* out) {
    if (threadIdx.x == 0) { ws[0] = 0.0; out[0] = 0.0f; }
}

__global__ void finalize_kernel(const double* __restrict__ ws,
                                float* __restrict__ out) {
    if (blockIdx.x == 0 && threadIdx.x == 0)
        out[0] = (float)ws[0];
}

extern "C" void kernel_launch(void* const* d_in, const int* in_sizes, int n_in,
                              void* d_out, int out_size, void* d_ws, size_t ws_size,
                              hipStream_t stream) {
    const float* mu = (const float*)d_in[0];
    const float* ls = (const float*)d_in[1];
    const int*   ei = (const int*)d_in[2];
    float* out = (float*)d_out;
    char*  wsb = (char*)d_ws;
    double* ws = (double*)d_ws;

    const int E = in_sizes[2] / 2;          // edge_index is [2, E]
    const int total4 = (NN * DD) / 4;

    if (ws_size >= (size_t)WA_END) {
        // ---- Tier A (int8 + dot4, no ssq) ----
        uint_t* ocurs = reinterpret_cast<uint_t*>(wsb + WA_OCURS);
        uint2*  oflow = reinterpret_cast<uint2*>(wsb + WA_OFLOW);
        unsigned int* mu8 = reinterpret_cast<unsigned int*>(wsb + WA_MU8);
        uint_t* pairs = reinterpret_cast<uint_t*>(wsb + WA_PAIRS);
        const int chunk = (E + NSCA - 1) / NSCA;

        hipMemsetAsync(wsb, 0, 1024, stream);          // acc + ocurs
        front_kernel<<<NKL + NSCA, 256, 0, stream>>>(mu, ls, mu8, ei, pairs,
                                                     oflow, ocurs, ws,
                                                     total4, E, chunk);
        ll_sortedA_kernel<<<2048, 256, 0, stream>>>(mu8, pairs, oflow, ocurs, ws);
    } else if (ws_size >= (size_t)WB_END) {
        // ---- Tier B (R7, fp8) ----
        uint_t* cursor = reinterpret_cast<uint_t*>(wsb + WB_CURSOR);
        unsigned int* mu8 = reinterpret_cast<unsigned int*>(wsb + WB_MU8);
        uint_t* pairs = reinterpret_cast<uint_t*>(wsb + WB_PAIRS);
        const int chunk = (E + NSCB - 1) / NSCB;

        hipMemsetAsync(wsb, 0, 16384, stream);
        frontB_kernel<<<NKLB + NSCB, 256, 0, stream>>>(mu, ls, mu8, ei, pairs,
                                                       cursor, ws, total4, E, chunk);
        ll_sortedB_kernel<<<2048, 256, 0, stream>>>(mu8, pairs, cursor, ws);
    } else {
        const bool use_fp8 = (ws_size >= (size_t)WB_MU8 + 12800000u);
        unsigned int* mu8 = use_fp8
            ? reinterpret_cast<unsigned int*>(wsb + WB_MU8) : nullptr;
        init_kernel<<<1, 64, 0, stream>>>(ws, out);
        kl_conv_kernel<<<1024, 256, 0, stream>>>(mu, ls, mu8, ws, total4);
        if (use_fp8)
            ll8_kernel<<<2048, 256, 0, stream>>>(mu8, ei, ws, E);
        else
            ll32_kernel<<<2048, 256, 0, stream>>>(mu, ei, ws, E);
    }
    finalize_kernel<<<1, 64, 0, stream>>>(ws, out);
}